// Round 2
// baseline (229.796 us; speedup 1.0000x reference)
//
#include <hip/hip_runtime.h>
#include <hip/hip_bf16.h>
#include <stdint.h>

typedef __bf16 bf16_t;
typedef __bf16 bf16x8 __attribute__((ext_vector_type(8)));
typedef __bf16 bf16x4 __attribute__((ext_vector_type(4)));
typedef float f32x4 __attribute__((ext_vector_type(4)));
typedef float f32x16 __attribute__((ext_vector_type(16)));
typedef uint32_t u32x4 __attribute__((ext_vector_type(4)));

#define XN 2097152   // x elements (2*1024*1024)
#define WN 1048576   // each weight (1024*1024)

typedef __attribute__((address_space(1))) const uint8_t* gas_ptr;
typedef __attribute__((address_space(3))) uint8_t* las_ptr;

static __device__ __forceinline__ uint16_t bfbits(float f) {
    bf16_t b = (bf16_t)f;
    return __builtin_bit_cast(uint16_t, b);
}

// ---------------- cast f32 -> bf16, all inputs fused ----------------
__global__ void cast_all_k(const float* __restrict__ x,
    const float* __restrict__ w0, const float* __restrict__ w1, const float* __restrict__ w2,
    const float* __restrict__ w3, const float* __restrict__ w4, const float* __restrict__ w5,
    const float* __restrict__ w6, bf16_t* __restrict__ dst)
{
    const int TOTC = (XN + 7 * WN) / 4;
    for (int c = blockIdx.x * blockDim.x + threadIdx.x; c < TOTC; c += gridDim.x * blockDim.x) {
        int el = c * 4;
        const float* s;
        if (el < XN) {
            s = x + el;
        } else {
            int r = el - XN;
            int wi = r >> 20;
            int off = r & (WN - 1);
            const float* wp = (wi == 0) ? w0 : (wi == 1) ? w1 : (wi == 2) ? w2
                             : (wi == 3) ? w3 : (wi == 4) ? w4 : (wi == 5) ? w5 : w6;
            s = wp + off;
        }
        float4 f = *(const float4*)s;
        bf16x4 o = { (bf16_t)f.x, (bf16_t)f.y, (bf16_t)f.z, (bf16_t)f.w };
        *(bf16x4*)(dst + el) = o;
    }
}

// ---------------- 128x128 bf16 MFMA GEMM (m97-style): C = A @ W^T + bias ----
// Linear LDS [128][64], global_load_lds width 16, 2 barriers per K-step.
// EPI 0: bf16 natural. EPI 1: z==0 bf16 *QSCALE (pre-scale q for exp2 softmax),
//        z==1 bf16 natural, z==2 V^T layout. EPI 2: f32 natural.
#define QSCALE 0.36067376022224085f   // 0.25 * log2(e)

template<int EPI>
__global__ __launch_bounds__(256)
void gemm128(const bf16_t* __restrict__ A0, const bf16_t* __restrict__ A1, const bf16_t* __restrict__ A2,
             const bf16_t* __restrict__ W0, const bf16_t* __restrict__ W1, const bf16_t* __restrict__ W2,
             const float* __restrict__ bias0, const float* __restrict__ bias1, const float* __restrict__ bias2,
             void* O0, void* O1, void* O2)
{
    const int z = blockIdx.z;
    const bf16_t* A = (z == 0) ? A0 : (z == 1) ? A1 : A2;
    const bf16_t* W = (z == 0) ? W0 : (z == 1) ? W1 : W2;
    const float* bias = (z == 0) ? bias0 : (z == 1) ? bias1 : bias2;
    void* Ov = (z == 0) ? O0 : (z == 1) ? O1 : O2;

    __shared__ bf16_t As[128 * 64];
    __shared__ bf16_t Bs[128 * 64];

    const int tid = threadIdx.x;
    const int lane = tid & 63, wave = tid >> 6;
    const int lo = lane & 15, hi = lane >> 4;
    const int wr = wave >> 1, wc = wave & 1;
    const int m0 = blockIdx.y * 128, n0 = blockIdx.x * 128;

    f32x4 acc[4][4] = {};

    for (int kt = 0; kt < 16; ++kt) {
        const int K0 = kt * 64;
        __syncthreads();   // previous tile fully consumed before overwrite
#pragma unroll
        for (int i = 0; i < 4; ++i) {
            const int cbase = i * 256 + wave * 64;       // wave-uniform chunk base
            const int c = cbase + lane;                  // per-lane chunk
            const int row = c >> 3, ko = c & 7;
            const bf16_t* ga = A + (size_t)(m0 + row) * 1024 + K0 + ko * 8;
            const bf16_t* gb = W + (size_t)(n0 + row) * 1024 + K0 + ko * 8;
            __builtin_amdgcn_global_load_lds((gas_ptr)ga, (las_ptr)(As + cbase * 8), 16, 0, 0);
            __builtin_amdgcn_global_load_lds((gas_ptr)gb, (las_ptr)(Bs + cbase * 8), 16, 0, 0);
        }
        __syncthreads();   // loads landed (vmcnt drained at barrier)
#pragma unroll
        for (int kk = 0; kk < 2; ++kk) {
            const int kb = kk * 32 + hi * 8;
            bf16x8 af[4], bfr[4];
#pragma unroll
            for (int m = 0; m < 4; ++m) af[m] = *(const bf16x8*)&As[(wr * 64 + m * 16 + lo) * 64 + kb];
#pragma unroll
            for (int n = 0; n < 4; ++n) bfr[n] = *(const bf16x8*)&Bs[(wc * 64 + n * 16 + lo) * 64 + kb];
#pragma unroll
            for (int m = 0; m < 4; ++m)
#pragma unroll
                for (int n = 0; n < 4; ++n)
                    acc[m][n] = __builtin_amdgcn_mfma_f32_16x16x32_bf16(af[m], bfr[n], acc[m][n], 0, 0, 0);
        }
    }

#pragma unroll
    for (int n = 0; n < 4; ++n) {
        const int col = n0 + wc * 64 + n * 16 + lo;
        const float bv = bias[col];
#pragma unroll
        for (int m = 0; m < 4; ++m) {
            const int r0 = m0 + wr * 64 + m * 16 + hi * 4;
            if (EPI == 2) {
                float* O = (float*)Ov;
#pragma unroll
                for (int r = 0; r < 4; ++r)
                    O[(size_t)(r0 + r) * 1024 + col] = acc[m][n][r] + bv;
            } else if (EPI == 0 || z < 2) {
                bf16_t* O = (bf16_t*)Ov;
                const float sc = (EPI == 1 && z == 0) ? QSCALE : 1.0f;
#pragma unroll
                for (int r = 0; r < 4; ++r)
                    O[(size_t)(r0 + r) * 1024 + col] = (bf16_t)((acc[m][n][r] + bv) * sc);
            } else {
                // V^T epilogue: col -> (c = col>>4, h = col&15); row -> (b = r0>>10, s = r0&1023)
                bf16_t* O = (bf16_t*)Ov;
                int cch = col >> 4, h = col & 15;
                int bb = r0 >> 10, ss = r0 & 1023;
                bf16x4 pv = { (bf16_t)(acc[m][n][0] + bv), (bf16_t)(acc[m][n][1] + bv),
                              (bf16_t)(acc[m][n][2] + bv), (bf16_t)(acc[m][n][3] + bv) };
                *(bf16x4*)(O + ((size_t)((cch * 2 + bb) * 16 + h)) * 1024 + ss) = pv;
            }
        }
    }
}

// ---------------- attention: per (c,b), 32x32x16 MFMA, swapped operands -----
// q pre-scaled by 0.25*log2(e) -> p = exp2(S^T) directly. K/V loads pipelined
// one iter ahead in registers. Cross-half exchange: 4 shfl_xor(32) (select the
// words each direction actually needs) instead of 8.
__global__ __launch_bounds__(256)
void attn_k(const bf16_t* __restrict__ qg, const bf16_t* __restrict__ kg,
            const bf16_t* __restrict__ vtg, bf16_t* __restrict__ y)
{
    const int c = blockIdx.y, b = blockIdx.z;
    const int lane = threadIdx.x & 63, wave = threadIdx.x >> 6;
    const int l31 = lane & 31, hi = lane >> 5;
    const int s = blockIdx.x * 128 + wave * 32 + l31;   // q row owned by this lane

    bf16x8 qf = *(const bf16x8*)(qg + ((size_t)(b * 1024 + s)) * 1024 + c * 16 + hi * 8);
    const bf16_t* kptr = kg + ((size_t)(b * 1024 + l31)) * 1024 + c * 16 + hi * 8;
    const bf16_t* vptr = vtg + ((size_t)((c * 2 + b) * 16 + (lane & 15))) * 1024 + hi * 8;

    f32x16 oacc = {};
    const f32x16 z16 = {};
    float den = 0.f;

    bf16x8 kf = *(const bf16x8*)(kptr);
    bf16x8 vf0 = *(const bf16x8*)(vptr);
    bf16x8 vf1 = *(const bf16x8*)(vptr + 16);

#pragma unroll 2
    for (int jt = 0; jt < 32; ++jt) {
        const int jn = (jt + 1) & 31;   // wraps on last iter; value unused
        bf16x8 kn  = *(const bf16x8*)(kptr + (size_t)jn * 32768);
        bf16x8 vn0 = *(const bf16x8*)(vptr + jn * 32);
        bf16x8 vn1 = *(const bf16x8*)(vptr + jn * 32 + 16);

        f32x16 st = __builtin_amdgcn_mfma_f32_32x32x16_bf16(kf, qf, z16, 0, 0, 0);

        float p[16];
#pragma unroll
        for (int r = 0; r < 16; ++r) { p[r] = exp2f(st[r]); den += p[r]; }

        uint32_t pk[8];
#pragma unroll
        for (int w = 0; w < 8; ++w)
            pk[w] = (uint32_t)bfbits(p[2 * w]) | ((uint32_t)bfbits(p[2 * w + 1]) << 16);

        // asymmetric exchange: hi=0 wants partner pk[0,1,4,5]; hi=1 wants pk[2,3,6,7]
        uint32_t t0 = hi ? pk[0] : pk[2];
        uint32_t t1 = hi ? pk[1] : pk[3];
        uint32_t t2 = hi ? pk[4] : pk[6];
        uint32_t t3 = hi ? pk[5] : pk[7];
        t0 = (uint32_t)__shfl_xor((int)t0, 32, 64);
        t1 = (uint32_t)__shfl_xor((int)t1, 32, 64);
        t2 = (uint32_t)__shfl_xor((int)t2, 32, 64);
        t3 = (uint32_t)__shfl_xor((int)t3, 32, 64);

        u32x4 f0v, f1v;
        f0v[0] = hi ? t0 : pk[0];  f0v[1] = hi ? t1 : pk[1];
        f0v[2] = hi ? pk[2] : t0;  f0v[3] = hi ? pk[3] : t1;
        f1v[0] = hi ? t2 : pk[4];  f1v[1] = hi ? t3 : pk[5];
        f1v[2] = hi ? pk[6] : t2;  f1v[3] = hi ? pk[7] : t3;
        bf16x8 pf0 = __builtin_bit_cast(bf16x8, f0v);
        bf16x8 pf1 = __builtin_bit_cast(bf16x8, f1v);

        oacc = __builtin_amdgcn_mfma_f32_32x32x16_bf16(vf0, pf0, oacc, 0, 0, 0);
        oacc = __builtin_amdgcn_mfma_f32_32x32x16_bf16(vf1, pf1, oacc, 0, 0, 0);

        kf = kn; vf0 = vn0; vf1 = vn1;
    }

    float dtot = den + __shfl_xor(den, 32, 64);
    float rinv = 1.0f / dtot;

    // scatter into y with the torch-reshape permutation
    const int bo = (c >> 1) & 1;
    const int so = (c & 1) * 512 + b * 256 + (s >> 2);
    const int f0i = (c >> 2) * 64 + (s & 3) * 16;
    bf16_t* yb = y + ((size_t)bo * 1024 + so) * 1024 + f0i + 4 * hi;
    bf16x4 o1 = { (bf16_t)(oacc[0] * rinv), (bf16_t)(oacc[1] * rinv),
                  (bf16_t)(oacc[2] * rinv), (bf16_t)(oacc[3] * rinv) };
    *(bf16x4*)(yb) = o1;
    bf16x4 o2 = { (bf16_t)(oacc[4] * rinv), (bf16_t)(oacc[5] * rinv),
                  (bf16_t)(oacc[6] * rinv), (bf16_t)(oacc[7] * rinv) };
    *(bf16x4*)(yb + 8) = o2;
}

extern "C" void kernel_launch(void* const* d_in, const int* in_sizes, int n_in,
                              void* d_out, int out_size, void* d_ws, size_t ws_size,
                              hipStream_t stream)
{
    (void)in_sizes; (void)n_in; (void)out_size; (void)ws_size;
    const float* x    = (const float*)d_in[0];
    const float* wq_b = (const float*)d_in[2];
    const float* wk_b = (const float*)d_in[4];
    const float* wv_b = (const float*)d_in[6];
    const float* vq_b = (const float*)d_in[8];
    const float* vk_b = (const float*)d_in[10];
    const float* vv_b = (const float*)d_in[12];
    const float* wo_b = (const float*)d_in[14];

    bf16_t* base = (bf16_t*)d_ws;
    bf16_t* xbf = base;                 // 2,097,152
    bf16_t* wbf = base + XN;            // 7 x 1,048,576 (wq,wk,wv,vq,vk,vv,wo)
    bf16_t* q1  = base + XN + 7 * WN;
    bf16_t* k1  = q1 + XN;
    bf16_t* v1  = k1 + XN;
    bf16_t* q   = v1 + XN;
    bf16_t* k   = q + XN;
    bf16_t* vT  = k + XN;
    bf16_t* y   = q1;                   // q1 dead after stage 2 -> reuse for y

    cast_all_k<<<dim3(2048), dim3(256), 0, stream>>>(
        x, (const float*)d_in[1], (const float*)d_in[3], (const float*)d_in[5],
        (const float*)d_in[7], (const float*)d_in[9], (const float*)d_in[11],
        (const float*)d_in[13], base);

    // stage 1: q1/k1/v1 = x @ {wq,wk,wv}^T + b
    gemm128<0><<<dim3(8, 16, 3), dim3(256), 0, stream>>>(
        xbf, xbf, xbf, wbf, wbf + WN, wbf + 2 * WN,
        wq_b, wk_b, wv_b, q1, k1, v1);

    // stage 2: q = scaled (q1 @ vq^T + b); k natural; vT transposed layout
    gemm128<1><<<dim3(8, 16, 3), dim3(256), 0, stream>>>(
        q1, k1, v1, wbf + 3 * WN, wbf + 4 * WN, wbf + 5 * WN,
        vq_b, vk_b, vv_b, q, k, vT);

    // attention + permuted scatter into y
    attn_k<<<dim3(8, 64, 2), dim3(256), 0, stream>>>(q, k, vT, y);

    // stage 3: out = y @ wo^T + b (f32)
    gemm128<2><<<dim3(8, 16, 1), dim3(256), 0, stream>>>(
        y, y, y, wbf + 6 * WN, wbf + 6 * WN, wbf + 6 * WN,
        wo_b, wo_b, wo_b, d_out, d_out, d_out);
}

// Round 3
// 199.861 us; speedup vs baseline: 1.1498x; 1.1498x over previous
//
#include <hip/hip_runtime.h>
#include <hip/hip_bf16.h>
#include <stdint.h>

typedef __bf16 bf16_t;
typedef __bf16 bf16x8 __attribute__((ext_vector_type(8)));
typedef __bf16 bf16x4 __attribute__((ext_vector_type(4)));
typedef float f32x4 __attribute__((ext_vector_type(4)));
typedef float f32x16 __attribute__((ext_vector_type(16)));
typedef uint32_t u32x4 __attribute__((ext_vector_type(4)));

#define XN 2097152   // x elements (2*1024*1024)
#define WN 1048576   // each weight (1024*1024)

typedef __attribute__((address_space(1))) const uint8_t* gas_ptr;
typedef __attribute__((address_space(3))) uint8_t* las_ptr;

static __device__ __forceinline__ uint16_t bfbits(float f) {
    bf16_t b = (bf16_t)f;
    return __builtin_bit_cast(uint16_t, b);
}

// ---------------- cast f32 -> bf16, all inputs fused ----------------
__global__ void cast_all_k(const float* __restrict__ x,
    const float* __restrict__ w0, const float* __restrict__ w1, const float* __restrict__ w2,
    const float* __restrict__ w3, const float* __restrict__ w4, const float* __restrict__ w5,
    const float* __restrict__ w6, bf16_t* __restrict__ dst)
{
    const int TOTC = (XN + 7 * WN) / 4;
    for (int c = blockIdx.x * blockDim.x + threadIdx.x; c < TOTC; c += gridDim.x * blockDim.x) {
        int el = c * 4;
        const float* s;
        if (el < XN) {
            s = x + el;
        } else {
            int r = el - XN;
            int wi = r >> 20;
            int off = r & (WN - 1);
            const float* wp = (wi == 0) ? w0 : (wi == 1) ? w1 : (wi == 2) ? w2
                             : (wi == 3) ? w3 : (wi == 4) ? w4 : (wi == 5) ? w5 : w6;
            s = wp + off;
        }
        float4 f = *(const float4*)s;
        bf16x4 o = { (bf16_t)f.x, (bf16_t)f.y, (bf16_t)f.z, (bf16_t)f.w };
        *(bf16x4*)(dst + el) = o;
    }
}

// ---------------- 128x64 bf16 MFMA GEMM: C = A @ W^T + bias ----------------
// Grid is 1D with XCD-bijective swizzle; n-tile fastest within an XCD chunk.
// EPI 0: bf16 natural (stage 1).
// EPI 1: z0 bf16*QSCALE natural; z1 K-fragment-order; z2 V-fragment-order.
// EPI 2: f32 natural (stage 3, z always 0, 256 blocks).
#define QSCALE 0.36067376022224085f   // 0.25 * log2(e)

template<int EPI>
__global__ __launch_bounds__(256)
void gemm128(const bf16_t* __restrict__ A0, const bf16_t* __restrict__ A1, const bf16_t* __restrict__ A2,
             const bf16_t* __restrict__ W0, const bf16_t* __restrict__ W1, const bf16_t* __restrict__ W2,
             const float* __restrict__ bias0, const float* __restrict__ bias1, const float* __restrict__ bias2,
             void* O0, void* O1, void* O2)
{
    const int bid = blockIdx.x;
    int z, mt, nt;
    if (EPI < 2) {
        const int swz = (bid & 7) * 96 + (bid >> 3);   // 768 blocks, bijective
        z = swz >> 8; mt = (swz >> 4) & 15; nt = swz & 15;
    } else {
        const int swz = (bid & 7) * 32 + (bid >> 3);   // 256 blocks
        z = 0; mt = swz >> 4; nt = swz & 15;
    }
    const bf16_t* A = (z == 0) ? A0 : (z == 1) ? A1 : A2;
    const bf16_t* W = (z == 0) ? W0 : (z == 1) ? W1 : W2;
    const float* bias = (z == 0) ? bias0 : (z == 1) ? bias1 : bias2;
    void* Ov = (z == 0) ? O0 : (z == 1) ? O1 : O2;

    __shared__ bf16_t As[128 * 64];
    __shared__ bf16_t Bs[64 * 64];

    const int tid = threadIdx.x;
    const int lane = tid & 63, wave = tid >> 6;
    const int lo = lane & 15, hi = lane >> 4;
    const int wr = wave >> 1, wc = wave & 1;
    const int m0 = mt * 128, n0 = nt * 64;

    f32x4 acc[4][2] = {};

    for (int kt = 0; kt < 16; ++kt) {
        const int K0 = kt * 64;
        __syncthreads();
#pragma unroll
        for (int i = 0; i < 4; ++i) {
            const int cbase = i * 256 + wave * 64;
            const int c = cbase + lane;
            const int row = c >> 3, ko = c & 7;
            const bf16_t* ga = A + (size_t)(m0 + row) * 1024 + K0 + ko * 8;
            __builtin_amdgcn_global_load_lds((gas_ptr)ga, (las_ptr)(As + cbase * 8), 16, 0, 0);
        }
#pragma unroll
        for (int i = 0; i < 2; ++i) {
            const int cbase = i * 256 + wave * 64;
            const int c = cbase + lane;
            const int row = c >> 3, ko = c & 7;
            const bf16_t* gb = W + (size_t)(n0 + row) * 1024 + K0 + ko * 8;
            __builtin_amdgcn_global_load_lds((gas_ptr)gb, (las_ptr)(Bs + cbase * 8), 16, 0, 0);
        }
        __syncthreads();
#pragma unroll
        for (int kk = 0; kk < 2; ++kk) {
            const int kb = kk * 32 + hi * 8;
            bf16x8 af[4], bfr[2];
#pragma unroll
            for (int m = 0; m < 4; ++m) af[m] = *(const bf16x8*)&As[(wr * 64 + m * 16 + lo) * 64 + kb];
#pragma unroll
            for (int n = 0; n < 2; ++n) bfr[n] = *(const bf16x8*)&Bs[(wc * 32 + n * 16 + lo) * 64 + kb];
#pragma unroll
            for (int m = 0; m < 4; ++m)
#pragma unroll
                for (int n = 0; n < 2; ++n)
                    acc[m][n] = __builtin_amdgcn_mfma_f32_16x16x32_bf16(af[m], bfr[n], acc[m][n], 0, 0, 0);
        }
    }

#pragma unroll
    for (int n = 0; n < 2; ++n) {
        const int col = n0 + wc * 32 + n * 16 + lo;
        const float bv = bias[col];
#pragma unroll
        for (int m = 0; m < 4; ++m) {
            const int r0 = m0 + wr * 64 + m * 16 + hi * 4;
            if (EPI == 2) {
                float* O = (float*)Ov;
#pragma unroll
                for (int r = 0; r < 4; ++r)
                    O[(size_t)(r0 + r) * 1024 + col] = acc[m][n][r] + bv;
            } else if (EPI == 0 || z == 0) {
                bf16_t* O = (bf16_t*)Ov;
                const float sc = (EPI == 1) ? QSCALE : 1.0f;
#pragma unroll
                for (int r = 0; r < 4; ++r)
                    O[(size_t)(r0 + r) * 1024 + col] = (bf16_t)((acc[m][n][r] + bv) * sc);
            } else if (z == 1) {
                // K fragment-order: chunk C = (s>>5)*64 + (h>>3)*32 + (s&31), elem C*8 + (h&7)
                bf16_t* O = (bf16_t*)Ov;
                const int cch = col >> 4, h = col & 15;
                const int bb = r0 >> 10;
                const size_t sb = (size_t)(cch * 2 + bb) * 16384;
#pragma unroll
                for (int r = 0; r < 4; ++r) {
                    const int ss = (r0 + r) & 1023;
                    const int C = ((ss >> 5) << 6) + ((h >> 3) << 5) + (ss & 31);
                    O[sb + C * 8 + (h & 7)] = (bf16_t)(acc[m][n][r] + bv);
                }
            } else {
                // V fragment-order: C = (s>>5)*64 + ((s>>4)&1)*32 + ((s>>3)&1)*16 + h, elem C*8 + (s&7)
                bf16_t* O = (bf16_t*)Ov;
                const int cch = col >> 4, h = col & 15;
                const int bb = r0 >> 10;
                const int s0 = r0 & 1023;
                const int C = ((s0 >> 5) << 6) + (((s0 >> 4) & 1) << 5) + (((s0 >> 3) & 1) << 4) + h;
                bf16x4 pv = { (bf16_t)(acc[m][n][0] + bv), (bf16_t)(acc[m][n][1] + bv),
                              (bf16_t)(acc[m][n][2] + bv), (bf16_t)(acc[m][n][3] + bv) };
                *(bf16x4*)(O + (size_t)(cch * 2 + bb) * 16384 + C * 8 + (s0 & 7)) = pv;
            }
        }
    }
}

// ---------------- attention: per (c,b), K/V staged in LDS fragment-order ----
// 8 waves x 32 q-rows. S^T = K.Q^T via 32x32x16; p = exp2 (q pre-scaled);
// P^T B-fragments via 4x v_permlane32_swap_b32; O^T = V^T.P^T.
__global__ __launch_bounds__(512)
void attn_k(const bf16_t* __restrict__ qg, const bf16_t* __restrict__ kfr,
            const bf16_t* __restrict__ vfr, bf16_t* __restrict__ y)
{
    __shared__ bf16_t lds[32768];   // [0,16384): K frags; [16384,32768): V frags

    const int c = blockIdx.y, b = blockIdx.z;
    const int tid = threadIdx.x;
    const int lane = tid & 63, wave = tid >> 6;
    const int l31 = lane & 31, hi = lane >> 5;
    const int s = blockIdx.x * 256 + wave * 32 + l31;

    const bf16_t* kb = kfr + (size_t)(c * 2 + b) * 16384;
    const bf16_t* vb = vfr + (size_t)(c * 2 + b) * 16384;
#pragma unroll
    for (int i = 0; i < 4; ++i) {
        const int cbase = i * 512 + wave * 64;
        __builtin_amdgcn_global_load_lds((gas_ptr)(kb + (cbase + lane) * 8),
                                         (las_ptr)((uint8_t*)lds + cbase * 16), 16, 0, 0);
        __builtin_amdgcn_global_load_lds((gas_ptr)(vb + (cbase + lane) * 8),
                                         (las_ptr)((uint8_t*)lds + 32768 + cbase * 16), 16, 0, 0);
    }

    bf16x8 qf = *(const bf16x8*)(qg + ((size_t)(b * 1024 + s)) * 1024 + c * 16 + hi * 8);

    __syncthreads();

    f32x16 oacc = {};
    const f32x16 z16 = {};
    float den = 0.f;
    const int vslot = ((lane >> 5) * 16 + (lane & 15)) * 8;   // broadcast-dup for l31>=16

    for (int jt = 0; jt < 32; ++jt) {
        bf16x8 kf  = *(const bf16x8*)&lds[jt * 512 + lane * 8];
        bf16x8 vf0 = *(const bf16x8*)&lds[16384 + jt * 512 + vslot];
        bf16x8 vf1 = *(const bf16x8*)&lds[16384 + jt * 512 + 256 + vslot];

        f32x16 st = __builtin_amdgcn_mfma_f32_32x32x16_bf16(kf, qf, z16, 0, 0, 0);

        float p[16];
#pragma unroll
        for (int r = 0; r < 16; ++r) { p[r] = __builtin_amdgcn_exp2f(st[r]); den += p[r]; }

        uint32_t pk[8];
#pragma unroll
        for (int w = 0; w < 8; ++w)
            pk[w] = (uint32_t)bfbits(p[2 * w]) | ((uint32_t)bfbits(p[2 * w + 1]) << 16);

        // cross-half exchange: swap(pk0,pk2) -> f0 words {0,2}; (pk1,pk3) -> {1,3};
        // (pk4,pk6) -> f1 {0,2}; (pk5,pk7) -> f1 {1,3}
        asm("v_permlane32_swap_b32 %0, %1" : "+v"(pk[0]), "+v"(pk[2]));
        asm("v_permlane32_swap_b32 %0, %1" : "+v"(pk[1]), "+v"(pk[3]));
        asm("v_permlane32_swap_b32 %0, %1" : "+v"(pk[4]), "+v"(pk[6]));
        asm("v_permlane32_swap_b32 %0, %1" : "+v"(pk[5]), "+v"(pk[7]));

        u32x4 f0v = { pk[0], pk[1], pk[2], pk[3] };
        u32x4 f1v = { pk[4], pk[5], pk[6], pk[7] };
        bf16x8 pf0 = __builtin_bit_cast(bf16x8, f0v);
        bf16x8 pf1 = __builtin_bit_cast(bf16x8, f1v);

        oacc = __builtin_amdgcn_mfma_f32_32x32x16_bf16(vf0, pf0, oacc, 0, 0, 0);
        oacc = __builtin_amdgcn_mfma_f32_32x32x16_bf16(vf1, pf1, oacc, 0, 0, 0);
    }

    float dtot = den + __shfl_xor(den, 32, 64);
    float rinv = 1.0f / dtot;

    // scatter into y with the torch-reshape permutation
    const int bo = (c >> 1) & 1;
    const int so = (c & 1) * 512 + b * 256 + (s >> 2);
    const int f0i = (c >> 2) * 64 + (s & 3) * 16;
    bf16_t* yb = y + ((size_t)bo * 1024 + so) * 1024 + f0i + 4 * hi;
    bf16x4 o1 = { (bf16_t)(oacc[0] * rinv), (bf16_t)(oacc[1] * rinv),
                  (bf16_t)(oacc[2] * rinv), (bf16_t)(oacc[3] * rinv) };
    *(bf16x4*)(yb) = o1;
    bf16x4 o2 = { (bf16_t)(oacc[4] * rinv), (bf16_t)(oacc[5] * rinv),
                  (bf16_t)(oacc[6] * rinv), (bf16_t)(oacc[7] * rinv) };
    *(bf16x4*)(yb + 8) = o2;
}

extern "C" void kernel_launch(void* const* d_in, const int* in_sizes, int n_in,
                              void* d_out, int out_size, void* d_ws, size_t ws_size,
                              hipStream_t stream)
{
    (void)in_sizes; (void)n_in; (void)out_size; (void)ws_size;
    const float* x    = (const float*)d_in[0];
    const float* wq_b = (const float*)d_in[2];
    const float* wk_b = (const float*)d_in[4];
    const float* wv_b = (const float*)d_in[6];
    const float* vq_b = (const float*)d_in[8];
    const float* vk_b = (const float*)d_in[10];
    const float* vv_b = (const float*)d_in[12];
    const float* wo_b = (const float*)d_in[14];

    bf16_t* base = (bf16_t*)d_ws;
    bf16_t* xbf = base;                 // 2,097,152
    bf16_t* wbf = base + XN;            // 7 x 1,048,576 (wq,wk,wv,vq,vk,vv,wo)
    bf16_t* q1  = base + XN + 7 * WN;
    bf16_t* k1  = q1 + XN;
    bf16_t* v1  = k1 + XN;
    bf16_t* q   = v1 + XN;
    bf16_t* kc  = q + XN;               // K fragment-order [128 slices][16384]
    bf16_t* vc  = kc + XN;              // V fragment-order
    bf16_t* y   = q1;                   // q1 dead after stage 2 -> reuse for y

    cast_all_k<<<dim3(2048), dim3(256), 0, stream>>>(
        x, (const float*)d_in[1], (const float*)d_in[3], (const float*)d_in[5],
        (const float*)d_in[7], (const float*)d_in[9], (const float*)d_in[11],
        (const float*)d_in[13], base);

    // stage 1: q1/k1/v1 = x @ {wq,wk,wv}^T + b
    gemm128<0><<<dim3(768), dim3(256), 0, stream>>>(
        xbf, xbf, xbf, wbf, wbf + WN, wbf + 2 * WN,
        wq_b, wk_b, wv_b, q1, k1, v1);

    // stage 2: q scaled natural; k/v in fragment order
    gemm128<1><<<dim3(768), dim3(256), 0, stream>>>(
        q1, k1, v1, wbf + 3 * WN, wbf + 4 * WN, wbf + 5 * WN,
        vq_b, vk_b, vv_b, q, kc, vc);

    // attention + permuted scatter into y
    attn_k<<<dim3(4, 64, 2), dim3(512), 0, stream>>>(q, kc, vc, y);

    // stage 3: out = y @ wo^T + b (f32)
    gemm128<2><<<dim3(256), dim3(256), 0, stream>>>(
        y, y, y, wbf + 6 * WN, wbf + 6 * WN, wbf + 6 * WN,
        wo_b, wo_b, wo_b, d_out, d_out, d_out);
}